// Round 3
// baseline (278.196 us; speedup 1.0000x reference)
//
#include <hip/hip_runtime.h>

// DCP reduction: out = sum_{b,r,c} wy(r)*wx(c)*|min_ch x[b,ch,r,c]|
// x: [16, 3, 1024, 1024] f32.  wy/wx = 2 at borders (r,c in {0,1023}), else 3.
// Derivation: 3x3 ones-conv (VALID over zero-padded image) + global sum ==
// per-pixel coverage-count weighting; pad pixels contribute 0 since the
// channel-min over the three zero pads is 0. K=3 hard-coded (win_size input).

#define DCP_B 16
#define DCP_H 1024
#define DCP_W 1024
#define DCP_HW (DCP_H * DCP_W)                   // 2^20
#define DCP_GROUPS_PER_IMG (DCP_HW / 4)          // 2^18 float4-groups per image
#define DCP_NGROUPS (DCP_B * DCP_GROUPS_PER_IMG) // 4,194,304

#define NBLOCKS 2048
#define NTHREADS 256
#define NTOTAL (NBLOCKS * NTHREADS)              // 524,288
#define ITERS (DCP_NGROUPS / NTOTAL)             // exactly 8 — no remainder

__global__ __launch_bounds__(NTHREADS) void dcp_partial_kernel(
    const float* __restrict__ x, double* __restrict__ part) {
  const unsigned tid = blockIdx.x * NTHREADS + threadIdx.x;

  float acc = 0.0f;  // per-thread partial: 8 groups, |values| ~ few; f32 exact enough

  #pragma unroll
  for (int it = 0; it < ITERS; ++it) {
    const unsigned g = tid + (unsigned)it * NTOTAL;
    const unsigned b = g >> 18;                   // g / (HW/4)
    const unsigned rem4 = g & (DCP_GROUPS_PER_IMG - 1);
    const unsigned rem = rem4 << 2;               // pixel offset within image
    const unsigned h = rem >> 10;                 // row
    const unsigned wcol = rem & (DCP_W - 1);      // start column (multiple of 4)

    const float* plane0 = x + (size_t)(b * 3 + 0) * DCP_HW + rem;
    const float4 a0 = *reinterpret_cast<const float4*>(plane0);
    const float4 a1 = *reinterpret_cast<const float4*>(plane0 + DCP_HW);
    const float4 a2 = *reinterpret_cast<const float4*>(plane0 + 2 * DCP_HW);

    // channel-min + abs per pixel (v_min3_f32 + and-mask)
    const float m0 = fabsf(fminf(fminf(a0.x, a1.x), a2.x));
    const float m1 = fabsf(fminf(fminf(a0.y, a1.y), a2.y));
    const float m2 = fabsf(fminf(fminf(a0.z, a1.z), a2.z));
    const float m3 = fabsf(fminf(fminf(a0.w, a1.w), a2.w));

    // column weights: col 0 (lane .x when wcol==0) and col 1023 (lane .w when
    // wcol==1020) get weight 2; all middle columns weight 3.
    const float wx0 = (wcol == 0) ? 2.0f : 3.0f;
    const float wx3 = (wcol == DCP_W - 4) ? 2.0f : 3.0f;
    const float wy = (h == 0 || h == DCP_H - 1) ? 2.0f : 3.0f;

    acc += wy * (m0 * wx0 + (m1 + m2) * 3.0f + m3 * wx3);
  }

  // block reduction in double: wave shuffle, then LDS across the 4 waves
  double d = (double)acc;
  #pragma unroll
  for (int off = 32; off > 0; off >>= 1) d += __shfl_down(d, off, 64);

  __shared__ double lds[NTHREADS / 64];
  const int lane = threadIdx.x & 63;
  const int wv = threadIdx.x >> 6;
  if (lane == 0) lds[wv] = d;
  __syncthreads();
  if (threadIdx.x == 0) {
    part[blockIdx.x] = lds[0] + lds[1] + lds[2] + lds[3];
  }
}

__global__ __launch_bounds__(256) void dcp_final_kernel(
    const double* __restrict__ part, float* __restrict__ out, int npart) {
  double d = 0.0;
  for (int i = threadIdx.x; i < npart; i += 256) d += part[i];
  #pragma unroll
  for (int off = 32; off > 0; off >>= 1) d += __shfl_down(d, off, 64);

  __shared__ double lds[4];
  const int lane = threadIdx.x & 63;
  const int wv = threadIdx.x >> 6;
  if (lane == 0) lds[wv] = d;
  __syncthreads();
  if (threadIdx.x == 0) out[0] = (float)(lds[0] + lds[1] + lds[2] + lds[3]);
}

extern "C" void kernel_launch(void* const* d_in, const int* in_sizes, int n_in,
                              void* d_out, int out_size, void* d_ws, size_t ws_size,
                              hipStream_t stream) {
  const float* x = (const float*)d_in[0];
  // d_in[1] is win_size==3; weight derivation hard-codes K=3.
  float* out = (float*)d_out;
  double* part = (double*)d_ws;  // NBLOCKS doubles = 16 KB << ws_size

  dcp_partial_kernel<<<NBLOCKS, NTHREADS, 0, stream>>>(x, part);
  dcp_final_kernel<<<1, 256, 0, stream>>>(part, out, NBLOCKS);
}